// Round 14
// baseline (160.422 us; speedup 1.0000x reference)
//
#include <hip/hip_runtime.h>

typedef unsigned short u16;
typedef __attribute__((ext_vector_type(8))) short bf16x8;   // MFMA A/B frag (8 bf16)
typedef __attribute__((ext_vector_type(4))) float f32x4;    // MFMA C/D frag

#define MFMA16(a, b, c) __builtin_amdgcn_mfma_f32_16x16x32_bf16((a), (b), (c), 0, 0, 0)

// async global->LDS, 16B per lane; LDS dest = wave-uniform base + lane*16
__device__ __forceinline__ void gll16(const void* g, void* l) {
    __builtin_amdgcn_global_load_lds(
        (const __attribute__((address_space(1))) unsigned int*)g,
        (__attribute__((address_space(3))) unsigned int*)l, 16, 0, 0);
}

__device__ __forceinline__ u16 f2b(float f) {   // f32 -> bf16 RNE (scalar)
    unsigned int u = __float_as_uint(f);
    u += 0x7fffu + ((u >> 16) & 1u);
    return (u16)(u >> 16);
}

// packed bf16x2 via HW converter (RNE)
__device__ __forceinline__ unsigned int pkcvt(float a, float b) {
    unsigned int r;
    asm("v_cvt_pk_bf16_f32 %0, %1, %2" : "=v"(r) : "v"(a), "v"(b));
    return r;
}

// ---------------------------------------------------------------- one cast kernel
__global__ __launch_bounds__(256) void cast_all(const float* __restrict__ x,
                                                const float* __restrict__ w0,
                                                const float* __restrict__ w1,
                                                const float* __restrict__ w2,
                                                const float* __restrict__ w3,
                                                u16* __restrict__ xb,
                                                u16* __restrict__ wb) {
    const int bid = blockIdx.x;
    const float* s; u16* d; int off;
    if (bid < 2048) { s = x; d = xb; off = bid; }
    else {
        const int wi = (bid - 2048) >> 9;
        s = (wi == 0) ? w0 : (wi == 1) ? w1 : (wi == 2) ? w2 : w3;
        d = wb + (size_t)wi * 1048576;
        off = (bid - 2048) & 511;
    }
    const int i = (off * 256 + threadIdx.x) * 8;
    float4 a = *(const float4*)(s + i);
    float4 b = *(const float4*)(s + i + 4);
    *(uint4*)(d + i) = make_uint4(pkcvt(a.x, a.y), pkcvt(a.z, a.w),
                                  pkcvt(b.x, b.y), pkcvt(b.z, b.w));
}

// ---------------------------------------------------------------- GEMM, dbuf K-loop
// R4-proven structure, frozen. QKV: 128x128, 768 blocks (3/CU). o-proj: 128x64,
// 512 blocks (2/CU), SLOTS=2.
template <int BM, int BN, int MODE, int SLOTS>
__global__ __launch_bounds__(256) void gemm_bt(const u16* __restrict__ A,
                                               const u16* __restrict__ W,
                                               void* __restrict__ Yv,
                                               u16* __restrict__ vT,
                                               int K, int ldY) {
    constexpr int MI = BM / 32, NJ = BN / 32;
    constexpr int ACH = BM / 16;
    constexpr int NPW = (BM + BN) / 64;
    __shared__ u16 As[2][SLOTS][BM * 32];
    __shared__ u16 Bs[2][SLOTS][BN * 32];
    const int t = threadIdx.x, w = t >> 6, lane = t & 63;
    const int quad = lane >> 4, m16 = lane & 15;
    const int wr = (w >> 1) * (BM / 2), wc = (w & 1) * (BN / 2);
    const int row0 = blockIdx.x * BM, col0 = blockIdx.y * BN;
    const int srow = lane >> 2, scol = (lane & 3) * 8;

    auto stage = [&](int buf, int slot, int k0) {
#pragma unroll
        for (int cc = 0; cc < NPW; ++cc) {
            const int c = w * NPW + cc;
            if (c < ACH)
                gll16(A + (size_t)(row0 + c * 16 + srow) * K + k0 + scol,
                      &As[buf][slot][c * 512]);
            else
                gll16(W + (size_t)(col0 + (c - ACH) * 16 + srow) * K + k0 + scol,
                      &Bs[buf][slot][(c - ACH) * 512]);
        }
    };

    f32x4 acc[MI][NJ];
#pragma unroll
    for (int i = 0; i < MI; ++i)
#pragma unroll
        for (int j = 0; j < NJ; ++j) acc[i][j] = (f32x4){0.f, 0.f, 0.f, 0.f};

    auto compute_tile = [&](int buf, int slot) {
        bf16x8 af[MI], bf[NJ];
#pragma unroll
        for (int i = 0; i < MI; ++i)
            af[i] = *(const bf16x8*)&As[buf][slot][(wr + i * 16 + m16) * 32 + quad * 8];
#pragma unroll
        for (int j = 0; j < NJ; ++j)
            bf[j] = *(const bf16x8*)&Bs[buf][slot][(wc + j * 16 + m16) * 32 + quad * 8];
#pragma unroll
        for (int i = 0; i < MI; ++i)
#pragma unroll
            for (int j = 0; j < NJ; ++j) acc[i][j] = MFMA16(af[i], bf[j], acc[i][j]);
    };

#pragma unroll
    for (int s = 0; s < SLOTS; ++s) stage(0, s, s * 32);
    const int ngroups = K / (32 * SLOTS);
    for (int g = 0; g < ngroups; ++g) {
        const int buf = g & 1;
        __syncthreads();
        const int kn = (g + 1) * SLOTS * 32;
        if (kn < K) {
#pragma unroll
            for (int s = 0; s < SLOTS; ++s) stage(buf ^ 1, s, kn + s * 32);
        }
#pragma unroll
        for (int s = 0; s < SLOTS; ++s) compute_tile(buf, s);
    }
    if constexpr (MODE == 0) {
#pragma unroll
        for (int i = 0; i < MI; ++i)
#pragma unroll
            for (int j = 0; j < NJ; ++j)
#pragma unroll
                for (int r = 0; r < 4; ++r)
                    ((float*)Yv)[(size_t)(row0 + wr + i * 16 + quad * 4 + r) * ldY +
                                 col0 + wc + j * 16 + m16] = acc[i][j][r];
    } else {
        if (col0 < 2048) {
            u16* qk = (u16*)Yv;
#pragma unroll
            for (int i = 0; i < MI; ++i)
#pragma unroll
                for (int j = 0; j < NJ; ++j)
#pragma unroll
                    for (int r = 0; r < 4; ++r)
                        qk[(size_t)(row0 + wr + i * 16 + quad * 4 + r) * 2048 +
                           col0 + wc + j * 16 + m16] = f2b(acc[i][j][r]);
        } else {
#pragma unroll
            for (int i = 0; i < MI; ++i) {
                const int rbase = row0 + wr + i * 16;
                const int bb = rbase >> 10;
                const int tok0 = (rbase & 1023) + quad * 4;
#pragma unroll
                for (int j = 0; j < NJ; ++j) {
                    const int vTrow = bb * 1024 + (col0 + wc + j * 16 + m16 - 2048);
                    *(uint2*)(vT + (size_t)vTrow * 1024 + tok0) =
                        make_uint2(pkcvt(acc[i][j][0], acc[i][j][1]),
                                   pkcvt(acc[i][j][2], acc[i][j][3]));
                }
            }
        }
    }
}

// ---------------------------------------------------------------- based attention
// R14 = R13 (swizzled, measured-best) + SLOT-INTERLEAVED pipeline: per 2-tile
// group, order is QK0 -> xform0 -> Ss-write0 -> QK1 -> PV0 -> xform1 -> W1 -> PV1.
// Slot1's 16 independent QK MFMAs sit between W0 and PV0, hiding the Ss
// write->read round-trip (the serial-path latency the swizzle exposed).
// Safety: Ss is wave-private; per-wave DS ops are in-order, so PV0's reads
// (program-order before W1) see slot-0 data. No barrier/layout changes.
__global__ __launch_bounds__(256) void based_attn(const u16* __restrict__ qkm,
                                                  const u16* __restrict__ vT,
                                                  u16* __restrict__ o) {
    __shared__ u16 ks[2][2][2][64][32];  // [buf][slot][dblk][key][32]
    __shared__ u16 vs[2][2][2][64][32];  // [buf][slot][kb][vdim][32 keys]
    __shared__ u16 SsA[2][64][32];       // [kb][qrow][32 keys] (wave-private rows)
    __shared__ u16 SsB[2][64][32];

    const int t = threadIdx.x, w = t >> 6, lane = t & 63;
    const int quad = lane >> 4, m16 = lane & 15;
    const int p = blockIdx.x, h = blockIdx.y, b = blockIdx.z;
    const int tA = p, tB = 15 - p;
    const int srow = lane >> 2;
    const int s8x = ((lane & 3) ^ ((lane >> 3) & 3)) * 8;  // pre-swizzled src slot
    const int sx = (m16 >> 1) & 3;                          // read-side XOR factor
    const int qrow = w * 16 + m16;       // this lane's q-row (local to tile)

    const size_t qbase = (size_t)b * 1024 * 2048 + h * 64;
    const size_t kbase = qbase + 1024;
    const size_t vbase = ((size_t)b * 1024 + h * 64) * 1024;

    bf16x8 qfA[2], qfB[2];
#pragma unroll
    for (int kd = 0; kd < 2; ++kd) {
        qfA[kd] = *(const bf16x8*)(qkm + qbase +
                   (size_t)(tA * 64 + qrow) * 2048 + kd * 32 + quad * 8);
        qfB[kd] = *(const bf16x8*)(qkm + qbase +
                   (size_t)(tB * 64 + qrow) * 2048 + kd * 32 + quad * 8);
    }

    auto stage_tile = [&](int kt, int buf, int slot) {
#pragma unroll
        for (int cc = 0; cc < 2; ++cc) {
            const int c = w * 2 + cc;
            const int blk = c >> 2, rc = c & 3;
            gll16(qkm + kbase + (size_t)(kt * 64 + rc * 16 + srow) * 2048 + blk * 32 + s8x,
                  &ks[buf][slot][blk][rc * 16][0]);
            gll16(vT + vbase + (size_t)(rc * 16 + srow) * 1024 + kt * 64 + blk * 32 + s8x,
                  &vs[buf][slot][blk][rc * 16][0]);
        }
    };

    bf16x8 ones;
#pragma unroll
    for (int e = 0; e < 8; ++e) ones[e] = (short)0x3F80;

    f32x4 numA[4], numB[4], denA, denB;
    denA = denB = (f32x4){0.f, 0.f, 0.f, 0.f};
#pragma unroll
    for (int j = 0; j < 4; ++j) numA[j] = numB[j] = (f32x4){0.f, 0.f, 0.f, 0.f};

    // Phase helpers -------------------------------------------------------
    auto qk_phase = [&](int buf, int slot, bool doA, f32x4 (&sA)[4], f32x4 (&sB)[4]) {
#pragma unroll
        for (int jk = 0; jk < 4; ++jk)
            sA[jk] = sB[jk] = (f32x4){0.f, 0.f, 0.f, 0.f};
        __builtin_amdgcn_s_setprio(1);
#pragma unroll
        for (int kd = 0; kd < 2; ++kd)
#pragma unroll
            for (int jk = 0; jk < 4; ++jk) {
                bf16x8 af = *(const bf16x8*)
                    &ks[buf][slot][kd][jk * 16 + m16][(quad ^ sx) * 8];
                sB[jk] = MFMA16(af, qfB[kd], sB[jk]);
                if (doA) sA[jk] = MFMA16(af, qfA[kd], sA[jk]);
            }
        __builtin_amdgcn_s_setprio(0);
    };

    auto tw_phase = [&](int kt, bool doA, f32x4 (&sA)[4], f32x4 (&sB)[4]) {
#pragma unroll
        for (int jk = 0; jk < 4; ++jk) {
            const int kl = jk * 16 + quad * 4;
            const int sidx = ((((jk & 1) * 2 + (quad >> 1)) ^ sx) << 3) +
                             ((quad & 1) << 2);
            float scB[4];
#pragma unroll
            for (int r = 0; r < 4; ++r) {
                const float u = fmaf(sB[jk][r], 0.125f, 1.0f);
                scB[r] = fmaf(u * 0.5f, u, 0.5f);
            }
            if (kt == tB) {
#pragma unroll
                for (int r = 0; r < 4; ++r)
                    if (kl + r > qrow) scB[r] = 0.f;
            }
            *(uint2*)&SsB[jk >> 1][qrow][sidx] =
                make_uint2(pkcvt(scB[0], scB[1]), pkcvt(scB[2], scB[3]));
            if (doA) {
                float scA[4];
#pragma unroll
                for (int r = 0; r < 4; ++r) {
                    const float u = fmaf(sA[jk][r], 0.125f, 1.0f);
                    scA[r] = fmaf(u * 0.5f, u, 0.5f);
                }
                if (kt == tA) {
#pragma unroll
                    for (int r = 0; r < 4; ++r)
                        if (kl + r > qrow) scA[r] = 0.f;
                }
                *(uint2*)&SsA[jk >> 1][qrow][sidx] =
                    make_uint2(pkcvt(scA[0], scA[1]), pkcvt(scA[2], scA[3]));
            }
        }
    };

    auto pv_phase = [&](int buf, int slot, bool doA) {
        __builtin_amdgcn_s_setprio(1);
#pragma unroll
        for (int kb = 0; kb < 2; ++kb) {
            bf16x8 vf[4];
#pragma unroll
            for (int j = 0; j < 4; ++j)
                vf[j] = *(const bf16x8*)
                    &vs[buf][slot][kb][j * 16 + m16][(quad ^ sx) * 8];
            bf16x8 sfB = *(const bf16x8*)&SsB[kb][qrow][(quad ^ sx) * 8];
#pragma unroll
            for (int j = 0; j < 4; ++j) numB[j] = MFMA16(sfB, vf[j], numB[j]);
            denB = MFMA16(sfB, ones, denB);
            if (doA) {
                bf16x8 sfA = *(const bf16x8*)&SsA[kb][qrow][(quad ^ sx) * 8];
#pragma unroll
                for (int j = 0; j < 4; ++j) numA[j] = MFMA16(sfA, vf[j], numA[j]);
                denA = MFMA16(sfA, ones, denA);
            }
        }
        __builtin_amdgcn_s_setprio(0);
    };

    stage_tile(0, 0, 0);
    stage_tile(1, 0, 1);

    const int ngroups = (tB + 2) >> 1;
    for (int g = 0; g < ngroups; ++g) {
        const int buf = g & 1;
        __syncthreads();
        const int kn = (g + 1) * 2;
        if (kn <= tB) {
            stage_tile(kn, buf ^ 1, 0);
            if (kn + 1 <= tB) stage_tile(kn + 1, buf ^ 1, 1);
        }
        const int kt0 = g * 2;
        const bool both = (kt0 + 1 <= tB);
        const bool doA0 = (kt0 <= tA), doA1 = (kt0 + 1 <= tA);
        f32x4 sA0[4], sB0[4], sA1[4], sB1[4];
        // slot-interleaved pipeline: QK0, T0+W0, QK1, PV0, T1+W1, PV1
        qk_phase(buf, 0, doA0, sA0, sB0);
        tw_phase(kt0, doA0, sA0, sB0);
        if (both) qk_phase(buf, 1, doA1, sA1, sB1);   // hides W0->PV0 round-trip
        pv_phase(buf, 0, doA0);
        if (both) {
            tw_phase(kt0 + 1, doA1, sA1, sB1);
            pv_phase(buf, 1, doA1);
        }
    }

#pragma unroll
    for (int r = 0; r < 4; ++r) {
        const float invA = 1.0f / denA[r], invB = 1.0f / denB[r];
        const int rowoff = w * 16 + quad * 4 + r;
        const size_t tokA = (size_t)(b * 1024 + tA * 64 + rowoff);
        const size_t tokB = (size_t)(b * 1024 + tB * 64 + rowoff);
#pragma unroll
        for (int j = 0; j < 4; ++j) {
            o[tokA * 1024 + h * 64 + j * 16 + m16] = f2b(numA[j][r] * invA);
            o[tokB * 1024 + h * 64 + j * 16 + m16] = f2b(numB[j][r] * invB);
        }
    }
}

// ---------------------------------------------------------------- launch
extern "C" void kernel_launch(void* const* d_in, const int* in_sizes, int n_in,
                              void* d_out, int out_size, void* d_ws, size_t ws_size,
                              hipStream_t stream) {
    const float* x  = (const float*)d_in[0];
    const float* Wq = (const float*)d_in[1];
    const float* Wk = (const float*)d_in[2];
    const float* Wv = (const float*)d_in[3];
    const float* Wo = (const float*)d_in[4];
    float* out = (float*)d_out;

    const size_t MEL = 4096ull * 1024ull;        // 4M elements
    u16* xb   = (u16*)d_ws;                      // 4096 x 1024
    u16* Wqkv = xb + MEL;                        // 3072 x 1024 (Wq|Wk|Wv rows)
    u16* Wob  = Wqkv + 3ull * 1024 * 1024;       // 1024 x 1024
    u16* qk   = Wob + 1024ull * 1024;            // 4096 x 2048 (q|k)
    u16* vT   = qk + 2ull * MEL;                 // [b*1024+h*64+vd][1024 tokens]
    u16* o    = vT + MEL;                        // 4096 x 1024

    cast_all<<<4096, 256, 0, stream>>>(x, Wq, Wk, Wv, Wo, xb, Wqkv);

    dim3 gq(32, 24);   // 128^2, 768 blocks = 3/CU (R4 proven)
    gemm_bt<128, 128, 1, 1><<<gq, 256, 0, stream>>>(xb, Wqkv, qk, vT, 1024, 2048);

    // R14: swizzled attn + slot-interleaved QK/PV pipeline
    dim3 ga(8, 16, 4); // pair index x heads x batch — uniform work per block
    based_attn<<<ga, 256, 0, stream>>>(qk, vT, o);

    dim3 go(32, 16);   // o-proj 128x64, 512 blocks = 2/CU (R4 proven)
    gemm_bt<128, 64, 0, 2><<<go, 256, 0, stream>>>(o, Wob, (void*)out, nullptr, 1024, 1024);
}

// Round 15
// 154.935 us; speedup vs baseline: 1.0354x; 1.0354x over previous
//
#include <hip/hip_runtime.h>

typedef unsigned short u16;
typedef __attribute__((ext_vector_type(8))) short bf16x8;   // MFMA A/B frag (8 bf16)
typedef __attribute__((ext_vector_type(4))) float f32x4;    // MFMA C/D frag

#define MFMA16(a, b, c) __builtin_amdgcn_mfma_f32_16x16x32_bf16((a), (b), (c), 0, 0, 0)

// async global->LDS, 16B per lane; LDS dest = wave-uniform base + lane*16
__device__ __forceinline__ void gll16(const void* g, void* l) {
    __builtin_amdgcn_global_load_lds(
        (const __attribute__((address_space(1))) unsigned int*)g,
        (__attribute__((address_space(3))) unsigned int*)l, 16, 0, 0);
}

__device__ __forceinline__ u16 f2b(float f) {   // f32 -> bf16 RNE (scalar)
    unsigned int u = __float_as_uint(f);
    u += 0x7fffu + ((u >> 16) & 1u);
    return (u16)(u >> 16);
}

// packed bf16x2 via HW converter (RNE)
__device__ __forceinline__ unsigned int pkcvt(float a, float b) {
    unsigned int r;
    asm("v_cvt_pk_bf16_f32 %0, %1, %2" : "=v"(r) : "v"(a), "v"(b));
    return r;
}

// ---------------------------------------------------------------- one cast kernel
__global__ __launch_bounds__(256) void cast_all(const float* __restrict__ x,
                                                const float* __restrict__ w0,
                                                const float* __restrict__ w1,
                                                const float* __restrict__ w2,
                                                const float* __restrict__ w3,
                                                u16* __restrict__ xb,
                                                u16* __restrict__ wb) {
    const int bid = blockIdx.x;
    const float* s; u16* d; int off;
    if (bid < 2048) { s = x; d = xb; off = bid; }
    else {
        const int wi = (bid - 2048) >> 9;
        s = (wi == 0) ? w0 : (wi == 1) ? w1 : (wi == 2) ? w2 : w3;
        d = wb + (size_t)wi * 1048576;
        off = (bid - 2048) & 511;
    }
    const int i = (off * 256 + threadIdx.x) * 8;
    float4 a = *(const float4*)(s + i);
    float4 b = *(const float4*)(s + i + 4);
    *(uint4*)(d + i) = make_uint4(pkcvt(a.x, a.y), pkcvt(a.z, a.w),
                                  pkcvt(b.x, b.y), pkcvt(b.z, b.w));
}

// ---------------------------------------------------------------- GEMM, dbuf K-loop
// R4-proven structure, frozen. QKV: 128x128, 768 blocks (3/CU). o-proj: 128x64,
// 512 blocks (2/CU), SLOTS=2.
template <int BM, int BN, int MODE, int SLOTS>
__global__ __launch_bounds__(256) void gemm_bt(const u16* __restrict__ A,
                                               const u16* __restrict__ W,
                                               void* __restrict__ Yv,
                                               u16* __restrict__ vT,
                                               int K, int ldY) {
    constexpr int MI = BM / 32, NJ = BN / 32;
    constexpr int ACH = BM / 16;
    constexpr int NPW = (BM + BN) / 64;
    __shared__ u16 As[2][SLOTS][BM * 32];
    __shared__ u16 Bs[2][SLOTS][BN * 32];
    const int t = threadIdx.x, w = t >> 6, lane = t & 63;
    const int quad = lane >> 4, m16 = lane & 15;
    const int wr = (w >> 1) * (BM / 2), wc = (w & 1) * (BN / 2);
    const int row0 = blockIdx.x * BM, col0 = blockIdx.y * BN;
    const int srow = lane >> 2, scol = (lane & 3) * 8;

    auto stage = [&](int buf, int slot, int k0) {
#pragma unroll
        for (int cc = 0; cc < NPW; ++cc) {
            const int c = w * NPW + cc;
            if (c < ACH)
                gll16(A + (size_t)(row0 + c * 16 + srow) * K + k0 + scol,
                      &As[buf][slot][c * 512]);
            else
                gll16(W + (size_t)(col0 + (c - ACH) * 16 + srow) * K + k0 + scol,
                      &Bs[buf][slot][(c - ACH) * 512]);
        }
    };

    f32x4 acc[MI][NJ];
#pragma unroll
    for (int i = 0; i < MI; ++i)
#pragma unroll
        for (int j = 0; j < NJ; ++j) acc[i][j] = (f32x4){0.f, 0.f, 0.f, 0.f};

    auto compute_tile = [&](int buf, int slot) {
        bf16x8 af[MI], bf[NJ];
#pragma unroll
        for (int i = 0; i < MI; ++i)
            af[i] = *(const bf16x8*)&As[buf][slot][(wr + i * 16 + m16) * 32 + quad * 8];
#pragma unroll
        for (int j = 0; j < NJ; ++j)
            bf[j] = *(const bf16x8*)&Bs[buf][slot][(wc + j * 16 + m16) * 32 + quad * 8];
#pragma unroll
        for (int i = 0; i < MI; ++i)
#pragma unroll
            for (int j = 0; j < NJ; ++j) acc[i][j] = MFMA16(af[i], bf[j], acc[i][j]);
    };

#pragma unroll
    for (int s = 0; s < SLOTS; ++s) stage(0, s, s * 32);
    const int ngroups = K / (32 * SLOTS);
    for (int g = 0; g < ngroups; ++g) {
        const int buf = g & 1;
        __syncthreads();
        const int kn = (g + 1) * SLOTS * 32;
        if (kn < K) {
#pragma unroll
            for (int s = 0; s < SLOTS; ++s) stage(buf ^ 1, s, kn + s * 32);
        }
#pragma unroll
        for (int s = 0; s < SLOTS; ++s) compute_tile(buf, s);
    }
    if constexpr (MODE == 0) {
#pragma unroll
        for (int i = 0; i < MI; ++i)
#pragma unroll
            for (int j = 0; j < NJ; ++j)
#pragma unroll
                for (int r = 0; r < 4; ++r)
                    ((float*)Yv)[(size_t)(row0 + wr + i * 16 + quad * 4 + r) * ldY +
                                 col0 + wc + j * 16 + m16] = acc[i][j][r];
    } else {
        if (col0 < 2048) {
            u16* qk = (u16*)Yv;
#pragma unroll
            for (int i = 0; i < MI; ++i)
#pragma unroll
                for (int j = 0; j < NJ; ++j)
#pragma unroll
                    for (int r = 0; r < 4; ++r)
                        qk[(size_t)(row0 + wr + i * 16 + quad * 4 + r) * 2048 +
                           col0 + wc + j * 16 + m16] = f2b(acc[i][j][r]);
        } else {
#pragma unroll
            for (int i = 0; i < MI; ++i) {
                const int rbase = row0 + wr + i * 16;
                const int bb = rbase >> 10;
                const int tok0 = (rbase & 1023) + quad * 4;
#pragma unroll
                for (int j = 0; j < NJ; ++j) {
                    const int vTrow = bb * 1024 + (col0 + wc + j * 16 + m16 - 2048);
                    *(uint2*)(vT + (size_t)vTrow * 1024 + tok0) =
                        make_uint2(pkcvt(acc[i][j][0], acc[i][j][1]),
                                   pkcvt(acc[i][j][2], acc[i][j][3]));
                }
            }
        }
    }
}

// ---------------------------------------------------------------- based attention
// R15 = R13 exact compute (measured-best: swizzled LDS, sequential slot order —
// R14 interleave regressed, reverted) + XCD CO-LOCATION: grid (16,4,8) with
// h=blockIdx.x, b=blockIdx.y, p=blockIdx.z. Linear block ID = h+16b+64p, so
// ID%8 = h%8: all 8 p-blocks sharing one (h,b) K/V slice (~256KB) land on the
// SAME XCD -> per-XCD working set 2 heads x 4 batches x 256KB = 2MB < 4MB L2.
// R13 FETCH was 55MB vs 24MB ideal (2.3x over-fetch from cross-XCD re-reads).
__global__ __launch_bounds__(256) void based_attn(const u16* __restrict__ qkm,
                                                  const u16* __restrict__ vT,
                                                  u16* __restrict__ o) {
    __shared__ u16 ks[2][2][2][64][32];  // [buf][slot][dblk][key][32]
    __shared__ u16 vs[2][2][2][64][32];  // [buf][slot][kb][vdim][32 keys]
    __shared__ u16 SsA[2][64][32];       // [kb][qrow][32 keys] (wave-private rows)
    __shared__ u16 SsB[2][64][32];

    const int t = threadIdx.x, w = t >> 6, lane = t & 63;
    const int quad = lane >> 4, m16 = lane & 15;
    const int h = blockIdx.x, b = blockIdx.y, p = blockIdx.z;   // XCD co-location
    const int tA = p, tB = 15 - p;
    const int srow = lane >> 2;
    const int s8x = ((lane & 3) ^ ((lane >> 3) & 3)) * 8;  // pre-swizzled src slot
    const int sx = (m16 >> 1) & 3;                          // read-side XOR factor
    const int qrow = w * 16 + m16;       // this lane's q-row (local to tile)

    const size_t qbase = (size_t)b * 1024 * 2048 + h * 64;
    const size_t kbase = qbase + 1024;
    const size_t vbase = ((size_t)b * 1024 + h * 64) * 1024;

    bf16x8 qfA[2], qfB[2];
#pragma unroll
    for (int kd = 0; kd < 2; ++kd) {
        qfA[kd] = *(const bf16x8*)(qkm + qbase +
                   (size_t)(tA * 64 + qrow) * 2048 + kd * 32 + quad * 8);
        qfB[kd] = *(const bf16x8*)(qkm + qbase +
                   (size_t)(tB * 64 + qrow) * 2048 + kd * 32 + quad * 8);
    }

    auto stage_tile = [&](int kt, int buf, int slot) {
#pragma unroll
        for (int cc = 0; cc < 2; ++cc) {
            const int c = w * 2 + cc;
            const int blk = c >> 2, rc = c & 3;
            gll16(qkm + kbase + (size_t)(kt * 64 + rc * 16 + srow) * 2048 + blk * 32 + s8x,
                  &ks[buf][slot][blk][rc * 16][0]);
            gll16(vT + vbase + (size_t)(rc * 16 + srow) * 1024 + kt * 64 + blk * 32 + s8x,
                  &vs[buf][slot][blk][rc * 16][0]);
        }
    };

    bf16x8 ones;
#pragma unroll
    for (int e = 0; e < 8; ++e) ones[e] = (short)0x3F80;

    f32x4 numA[4], numB[4], denA, denB;
    denA = denB = (f32x4){0.f, 0.f, 0.f, 0.f};
#pragma unroll
    for (int j = 0; j < 4; ++j) numA[j] = numB[j] = (f32x4){0.f, 0.f, 0.f, 0.f};

    auto compute = [&](int buf, int slot, int kt) {
        const bool doA = (kt <= tA);
        f32x4 sA[4], sB[4];
#pragma unroll
        for (int jk = 0; jk < 4; ++jk)
            sA[jk] = sB[jk] = (f32x4){0.f, 0.f, 0.f, 0.f};
        __builtin_amdgcn_s_setprio(1);
#pragma unroll
        for (int kd = 0; kd < 2; ++kd)
#pragma unroll
            for (int jk = 0; jk < 4; ++jk) {
                bf16x8 af = *(const bf16x8*)
                    &ks[buf][slot][kd][jk * 16 + m16][(quad ^ sx) * 8];
                sB[jk] = MFMA16(af, qfB[kd], sB[jk]);
                if (doA) sA[jk] = MFMA16(af, qfA[kd], sA[jk]);
            }
        __builtin_amdgcn_s_setprio(0);
#pragma unroll
        for (int jk = 0; jk < 4; ++jk) {
            const int kl = jk * 16 + quad * 4;
            const int sidx = ((((jk & 1) * 2 + (quad >> 1)) ^ sx) << 3) +
                             ((quad & 1) << 2);
            float scB[4];
#pragma unroll
            for (int r = 0; r < 4; ++r) {
                const float u = fmaf(sB[jk][r], 0.125f, 1.0f);
                scB[r] = fmaf(u * 0.5f, u, 0.5f);
            }
            if (kt == tB) {
#pragma unroll
                for (int r = 0; r < 4; ++r)
                    if (kl + r > qrow) scB[r] = 0.f;
            }
            *(uint2*)&SsB[jk >> 1][qrow][sidx] =
                make_uint2(pkcvt(scB[0], scB[1]), pkcvt(scB[2], scB[3]));
            if (doA) {
                float scA[4];
#pragma unroll
                for (int r = 0; r < 4; ++r) {
                    const float u = fmaf(sA[jk][r], 0.125f, 1.0f);
                    scA[r] = fmaf(u * 0.5f, u, 0.5f);
                }
                if (kt == tA) {
#pragma unroll
                    for (int r = 0; r < 4; ++r)
                        if (kl + r > qrow) scA[r] = 0.f;
                }
                *(uint2*)&SsA[jk >> 1][qrow][sidx] =
                    make_uint2(pkcvt(scA[0], scA[1]), pkcvt(scA[2], scA[3]));
            }
        }
        __builtin_amdgcn_s_setprio(1);
#pragma unroll
        for (int kb = 0; kb < 2; ++kb) {
            bf16x8 vf[4];
#pragma unroll
            for (int j = 0; j < 4; ++j)
                vf[j] = *(const bf16x8*)
                    &vs[buf][slot][kb][j * 16 + m16][(quad ^ sx) * 8];
            bf16x8 sfB = *(const bf16x8*)&SsB[kb][qrow][(quad ^ sx) * 8];
#pragma unroll
            for (int j = 0; j < 4; ++j) numB[j] = MFMA16(sfB, vf[j], numB[j]);
            denB = MFMA16(sfB, ones, denB);
            if (doA) {
                bf16x8 sfA = *(const bf16x8*)&SsA[kb][qrow][(quad ^ sx) * 8];
#pragma unroll
                for (int j = 0; j < 4; ++j) numA[j] = MFMA16(sfA, vf[j], numA[j]);
                denA = MFMA16(sfA, ones, denA);
            }
        }
        __builtin_amdgcn_s_setprio(0);
    };

    stage_tile(0, 0, 0);
    stage_tile(1, 0, 1);

    const int ngroups = (tB + 2) >> 1;
    for (int g = 0; g < ngroups; ++g) {
        const int buf = g & 1;
        __syncthreads();
        const int kn = (g + 1) * 2;
        if (kn <= tB) {
            stage_tile(kn, buf ^ 1, 0);
            if (kn + 1 <= tB) stage_tile(kn + 1, buf ^ 1, 1);
        }
        const int kt0 = g * 2;
        compute(buf, 0, kt0);
        if (kt0 + 1 <= tB) compute(buf, 1, kt0 + 1);
    }

#pragma unroll
    for (int r = 0; r < 4; ++r) {
        const float invA = 1.0f / denA[r], invB = 1.0f / denB[r];
        const int rowoff = w * 16 + quad * 4 + r;
        const size_t tokA = (size_t)(b * 1024 + tA * 64 + rowoff);
        const size_t tokB = (size_t)(b * 1024 + tB * 64 + rowoff);
#pragma unroll
        for (int j = 0; j < 4; ++j) {
            o[tokA * 1024 + h * 64 + j * 16 + m16] = f2b(numA[j][r] * invA);
            o[tokB * 1024 + h * 64 + j * 16 + m16] = f2b(numB[j][r] * invB);
        }
    }
}

// ---------------------------------------------------------------- launch
extern "C" void kernel_launch(void* const* d_in, const int* in_sizes, int n_in,
                              void* d_out, int out_size, void* d_ws, size_t ws_size,
                              hipStream_t stream) {
    const float* x  = (const float*)d_in[0];
    const float* Wq = (const float*)d_in[1];
    const float* Wk = (const float*)d_in[2];
    const float* Wv = (const float*)d_in[3];
    const float* Wo = (const float*)d_in[4];
    float* out = (float*)d_out;

    const size_t MEL = 4096ull * 1024ull;        // 4M elements
    u16* xb   = (u16*)d_ws;                      // 4096 x 1024
    u16* Wqkv = xb + MEL;                        // 3072 x 1024 (Wq|Wk|Wv rows)
    u16* Wob  = Wqkv + 3ull * 1024 * 1024;       // 1024 x 1024
    u16* qk   = Wob + 1024ull * 1024;            // 4096 x 2048 (q|k)
    u16* vT   = qk + 2ull * MEL;                 // [b*1024+h*64+vd][1024 tokens]
    u16* o    = vT + MEL;                        // 4096 x 1024

    cast_all<<<4096, 256, 0, stream>>>(x, Wq, Wk, Wv, Wo, xb, Wqkv);

    dim3 gq(32, 24);   // 128^2, 768 blocks = 3/CU (R4 proven)
    gemm_bt<128, 128, 1, 1><<<gq, 256, 0, stream>>>(xb, Wqkv, qk, vT, 1024, 2048);

    // R15: R13 attn + XCD co-location grid (h,b,p) — K/V sharers on one XCD
    dim3 ga(16, 4, 8); // heads x batch x pair index
    based_attn<<<ga, 256, 0, stream>>>(qk, vT, o);

    dim3 go(32, 16);   // o-proj 128x64, 512 blocks = 2/CU (R4 proven)
    gemm_bt<128, 64, 0, 2><<<go, 256, 0, stream>>>(o, Wob, (void*)out, nullptr, 1024, 1024);
}

// Round 16
// 153.575 us; speedup vs baseline: 1.0446x; 1.0089x over previous
//
#include <hip/hip_runtime.h>

typedef unsigned short u16;
typedef __attribute__((ext_vector_type(8))) short bf16x8;   // MFMA A/B frag (8 bf16)
typedef __attribute__((ext_vector_type(4))) float f32x4;    // MFMA C/D frag

#define MFMA16(a, b, c) __builtin_amdgcn_mfma_f32_16x16x32_bf16((a), (b), (c), 0, 0, 0)

// async global->LDS, 16B per lane; LDS dest = wave-uniform base + lane*16
__device__ __forceinline__ void gll16(const void* g, void* l) {
    __builtin_amdgcn_global_load_lds(
        (const __attribute__((address_space(1))) unsigned int*)g,
        (__attribute__((address_space(3))) unsigned int*)l, 16, 0, 0);
}

__device__ __forceinline__ u16 f2b(float f) {   // f32 -> bf16 RNE (scalar)
    unsigned int u = __float_as_uint(f);
    u += 0x7fffu + ((u >> 16) & 1u);
    return (u16)(u >> 16);
}

// packed bf16x2 via HW converter (RNE)
__device__ __forceinline__ unsigned int pkcvt(float a, float b) {
    unsigned int r;
    asm("v_cvt_pk_bf16_f32 %0, %1, %2" : "=v"(r) : "v"(a), "v"(b));
    return r;
}

// ---------------------------------------------------------------- one cast kernel
__global__ __launch_bounds__(256) void cast_all(const float* __restrict__ x,
                                                const float* __restrict__ w0,
                                                const float* __restrict__ w1,
                                                const float* __restrict__ w2,
                                                const float* __restrict__ w3,
                                                u16* __restrict__ xb,
                                                u16* __restrict__ wb) {
    const int bid = blockIdx.x;
    const float* s; u16* d; int off;
    if (bid < 2048) { s = x; d = xb; off = bid; }
    else {
        const int wi = (bid - 2048) >> 9;
        s = (wi == 0) ? w0 : (wi == 1) ? w1 : (wi == 2) ? w2 : w3;
        d = wb + (size_t)wi * 1048576;
        off = (bid - 2048) & 511;
    }
    const int i = (off * 256 + threadIdx.x) * 8;
    float4 a = *(const float4*)(s + i);
    float4 b = *(const float4*)(s + i + 4);
    *(uint4*)(d + i) = make_uint4(pkcvt(a.x, a.y), pkcvt(a.z, a.w),
                                  pkcvt(b.x, b.y), pkcvt(b.z, b.w));
}

// ---------------------------------------------------------------- GEMM, dbuf K-loop
// R4-proven structure, frozen. QKV: 128x128, 768 blocks (3/CU). o-proj: 128x64,
// 512 blocks (2/CU), SLOTS=2.
// R16: XSWZ=1 (QKV only, grid 32x24) — XCD super-tiling. Default ID%8=bx%8
// co-locates A-sharers but spreads each 256KB B-panel over all 8 XCDs (7MB/XCD
// read set). Bijective remap: xcd=id&7, l=id>>3, bx=(xcd&3)*8+(l&7),
// by=(xcd>>2)*12+(l>>3) -> each XCD owns an 8x12 region: 2MB A + 3MB B = 5MB,
// B-panel sharers become L2 hits. (o-proj partition math is null either way.)
template <int BM, int BN, int MODE, int SLOTS, int XSWZ>
__global__ __launch_bounds__(256) void gemm_bt(const u16* __restrict__ A,
                                               const u16* __restrict__ W,
                                               void* __restrict__ Yv,
                                               u16* __restrict__ vT,
                                               int K, int ldY) {
    constexpr int MI = BM / 32, NJ = BN / 32;
    constexpr int ACH = BM / 16;
    constexpr int NPW = (BM + BN) / 64;
    __shared__ u16 As[2][SLOTS][BM * 32];
    __shared__ u16 Bs[2][SLOTS][BN * 32];
    const int t = threadIdx.x, w = t >> 6, lane = t & 63;
    const int quad = lane >> 4, m16 = lane & 15;
    const int wr = (w >> 1) * (BM / 2), wc = (w & 1) * (BN / 2);
    int bx = blockIdx.x, by = blockIdx.y;
    if constexpr (XSWZ) {                   // requires grid (32,24)
        const int id = blockIdx.x + 32 * blockIdx.y;
        const int xcd = id & 7, l = id >> 3;
        bx = (xcd & 3) * 8 + (l & 7);
        by = (xcd >> 2) * 12 + (l >> 3);
    }
    const int row0 = bx * BM, col0 = by * BN;
    const int srow = lane >> 2, scol = (lane & 3) * 8;

    auto stage = [&](int buf, int slot, int k0) {
#pragma unroll
        for (int cc = 0; cc < NPW; ++cc) {
            const int c = w * NPW + cc;
            if (c < ACH)
                gll16(A + (size_t)(row0 + c * 16 + srow) * K + k0 + scol,
                      &As[buf][slot][c * 512]);
            else
                gll16(W + (size_t)(col0 + (c - ACH) * 16 + srow) * K + k0 + scol,
                      &Bs[buf][slot][(c - ACH) * 512]);
        }
    };

    f32x4 acc[MI][NJ];
#pragma unroll
    for (int i = 0; i < MI; ++i)
#pragma unroll
        for (int j = 0; j < NJ; ++j) acc[i][j] = (f32x4){0.f, 0.f, 0.f, 0.f};

    auto compute_tile = [&](int buf, int slot) {
        bf16x8 af[MI], bf[NJ];
#pragma unroll
        for (int i = 0; i < MI; ++i)
            af[i] = *(const bf16x8*)&As[buf][slot][(wr + i * 16 + m16) * 32 + quad * 8];
#pragma unroll
        for (int j = 0; j < NJ; ++j)
            bf[j] = *(const bf16x8*)&Bs[buf][slot][(wc + j * 16 + m16) * 32 + quad * 8];
#pragma unroll
        for (int i = 0; i < MI; ++i)
#pragma unroll
            for (int j = 0; j < NJ; ++j) acc[i][j] = MFMA16(af[i], bf[j], acc[i][j]);
    };

#pragma unroll
    for (int s = 0; s < SLOTS; ++s) stage(0, s, s * 32);
    const int ngroups = K / (32 * SLOTS);
    for (int g = 0; g < ngroups; ++g) {
        const int buf = g & 1;
        __syncthreads();
        const int kn = (g + 1) * SLOTS * 32;
        if (kn < K) {
#pragma unroll
            for (int s = 0; s < SLOTS; ++s) stage(buf ^ 1, s, kn + s * 32);
        }
#pragma unroll
        for (int s = 0; s < SLOTS; ++s) compute_tile(buf, s);
    }
    if constexpr (MODE == 0) {
#pragma unroll
        for (int i = 0; i < MI; ++i)
#pragma unroll
            for (int j = 0; j < NJ; ++j)
#pragma unroll
                for (int r = 0; r < 4; ++r)
                    ((float*)Yv)[(size_t)(row0 + wr + i * 16 + quad * 4 + r) * ldY +
                                 col0 + wc + j * 16 + m16] = acc[i][j][r];
    } else {
        if (col0 < 2048) {
            u16* qk = (u16*)Yv;
#pragma unroll
            for (int i = 0; i < MI; ++i)
#pragma unroll
                for (int j = 0; j < NJ; ++j)
#pragma unroll
                    for (int r = 0; r < 4; ++r)
                        qk[(size_t)(row0 + wr + i * 16 + quad * 4 + r) * 2048 +
                           col0 + wc + j * 16 + m16] = f2b(acc[i][j][r]);
        } else {
#pragma unroll
            for (int i = 0; i < MI; ++i) {
                const int rbase = row0 + wr + i * 16;
                const int bb = rbase >> 10;
                const int tok0 = (rbase & 1023) + quad * 4;
#pragma unroll
                for (int j = 0; j < NJ; ++j) {
                    const int vTrow = bb * 1024 + (col0 + wc + j * 16 + m16 - 2048);
                    *(uint2*)(vT + (size_t)vTrow * 1024 + tok0) =
                        make_uint2(pkcvt(acc[i][j][0], acc[i][j][1]),
                                   pkcvt(acc[i][j][2], acc[i][j][3]));
                }
            }
        }
    }
}

// ---------------------------------------------------------------- based attention
// R15 best (frozen): R13 swizzled compute + XCD co-location grid (16,4,8) with
// h=blockIdx.x, b=blockIdx.y, p=blockIdx.z — all 8 K/V-sharing blocks per (h,b)
// on one XCD (2MB/XCD working set). Measured: 158.7 -> 154.9 us.
__global__ __launch_bounds__(256) void based_attn(const u16* __restrict__ qkm,
                                                  const u16* __restrict__ vT,
                                                  u16* __restrict__ o) {
    __shared__ u16 ks[2][2][2][64][32];  // [buf][slot][dblk][key][32]
    __shared__ u16 vs[2][2][2][64][32];  // [buf][slot][kb][vdim][32 keys]
    __shared__ u16 SsA[2][64][32];       // [kb][qrow][32 keys] (wave-private rows)
    __shared__ u16 SsB[2][64][32];

    const int t = threadIdx.x, w = t >> 6, lane = t & 63;
    const int quad = lane >> 4, m16 = lane & 15;
    const int h = blockIdx.x, b = blockIdx.y, p = blockIdx.z;   // XCD co-location
    const int tA = p, tB = 15 - p;
    const int srow = lane >> 2;
    const int s8x = ((lane & 3) ^ ((lane >> 3) & 3)) * 8;  // pre-swizzled src slot
    const int sx = (m16 >> 1) & 3;                          // read-side XOR factor
    const int qrow = w * 16 + m16;       // this lane's q-row (local to tile)

    const size_t qbase = (size_t)b * 1024 * 2048 + h * 64;
    const size_t kbase = qbase + 1024;
    const size_t vbase = ((size_t)b * 1024 + h * 64) * 1024;

    bf16x8 qfA[2], qfB[2];
#pragma unroll
    for (int kd = 0; kd < 2; ++kd) {
        qfA[kd] = *(const bf16x8*)(qkm + qbase +
                   (size_t)(tA * 64 + qrow) * 2048 + kd * 32 + quad * 8);
        qfB[kd] = *(const bf16x8*)(qkm + qbase +
                   (size_t)(tB * 64 + qrow) * 2048 + kd * 32 + quad * 8);
    }

    auto stage_tile = [&](int kt, int buf, int slot) {
#pragma unroll
        for (int cc = 0; cc < 2; ++cc) {
            const int c = w * 2 + cc;
            const int blk = c >> 2, rc = c & 3;
            gll16(qkm + kbase + (size_t)(kt * 64 + rc * 16 + srow) * 2048 + blk * 32 + s8x,
                  &ks[buf][slot][blk][rc * 16][0]);
            gll16(vT + vbase + (size_t)(rc * 16 + srow) * 1024 + kt * 64 + blk * 32 + s8x,
                  &vs[buf][slot][blk][rc * 16][0]);
        }
    };

    bf16x8 ones;
#pragma unroll
    for (int e = 0; e < 8; ++e) ones[e] = (short)0x3F80;

    f32x4 numA[4], numB[4], denA, denB;
    denA = denB = (f32x4){0.f, 0.f, 0.f, 0.f};
#pragma unroll
    for (int j = 0; j < 4; ++j) numA[j] = numB[j] = (f32x4){0.f, 0.f, 0.f, 0.f};

    auto compute = [&](int buf, int slot, int kt) {
        const bool doA = (kt <= tA);
        f32x4 sA[4], sB[4];
#pragma unroll
        for (int jk = 0; jk < 4; ++jk)
            sA[jk] = sB[jk] = (f32x4){0.f, 0.f, 0.f, 0.f};
        __builtin_amdgcn_s_setprio(1);
#pragma unroll
        for (int kd = 0; kd < 2; ++kd)
#pragma unroll
            for (int jk = 0; jk < 4; ++jk) {
                bf16x8 af = *(const bf16x8*)
                    &ks[buf][slot][kd][jk * 16 + m16][(quad ^ sx) * 8];
                sB[jk] = MFMA16(af, qfB[kd], sB[jk]);
                if (doA) sA[jk] = MFMA16(af, qfA[kd], sA[jk]);
            }
        __builtin_amdgcn_s_setprio(0);
#pragma unroll
        for (int jk = 0; jk < 4; ++jk) {
            const int kl = jk * 16 + quad * 4;
            const int sidx = ((((jk & 1) * 2 + (quad >> 1)) ^ sx) << 3) +
                             ((quad & 1) << 2);
            float scB[4];
#pragma unroll
            for (int r = 0; r < 4; ++r) {
                const float u = fmaf(sB[jk][r], 0.125f, 1.0f);
                scB[r] = fmaf(u * 0.5f, u, 0.5f);
            }
            if (kt == tB) {
#pragma unroll
                for (int r = 0; r < 4; ++r)
                    if (kl + r > qrow) scB[r] = 0.f;
            }
            *(uint2*)&SsB[jk >> 1][qrow][sidx] =
                make_uint2(pkcvt(scB[0], scB[1]), pkcvt(scB[2], scB[3]));
            if (doA) {
                float scA[4];
#pragma unroll
                for (int r = 0; r < 4; ++r) {
                    const float u = fmaf(sA[jk][r], 0.125f, 1.0f);
                    scA[r] = fmaf(u * 0.5f, u, 0.5f);
                }
                if (kt == tA) {
#pragma unroll
                    for (int r = 0; r < 4; ++r)
                        if (kl + r > qrow) scA[r] = 0.f;
                }
                *(uint2*)&SsA[jk >> 1][qrow][sidx] =
                    make_uint2(pkcvt(scA[0], scA[1]), pkcvt(scA[2], scA[3]));
            }
        }
        __builtin_amdgcn_s_setprio(1);
#pragma unroll
        for (int kb = 0; kb < 2; ++kb) {
            bf16x8 vf[4];
#pragma unroll
            for (int j = 0; j < 4; ++j)
                vf[j] = *(const bf16x8*)
                    &vs[buf][slot][kb][j * 16 + m16][(quad ^ sx) * 8];
            bf16x8 sfB = *(const bf16x8*)&SsB[kb][qrow][(quad ^ sx) * 8];
#pragma unroll
            for (int j = 0; j < 4; ++j) numB[j] = MFMA16(sfB, vf[j], numB[j]);
            denB = MFMA16(sfB, ones, denB);
            if (doA) {
                bf16x8 sfA = *(const bf16x8*)&SsA[kb][qrow][(quad ^ sx) * 8];
#pragma unroll
                for (int j = 0; j < 4; ++j) numA[j] = MFMA16(sfA, vf[j], numA[j]);
                denA = MFMA16(sfA, ones, denA);
            }
        }
        __builtin_amdgcn_s_setprio(0);
    };

    stage_tile(0, 0, 0);
    stage_tile(1, 0, 1);

    const int ngroups = (tB + 2) >> 1;
    for (int g = 0; g < ngroups; ++g) {
        const int buf = g & 1;
        __syncthreads();
        const int kn = (g + 1) * 2;
        if (kn <= tB) {
            stage_tile(kn, buf ^ 1, 0);
            if (kn + 1 <= tB) stage_tile(kn + 1, buf ^ 1, 1);
        }
        const int kt0 = g * 2;
        compute(buf, 0, kt0);
        if (kt0 + 1 <= tB) compute(buf, 1, kt0 + 1);
    }

#pragma unroll
    for (int r = 0; r < 4; ++r) {
        const float invA = 1.0f / denA[r], invB = 1.0f / denB[r];
        const int rowoff = w * 16 + quad * 4 + r;
        const size_t tokA = (size_t)(b * 1024 + tA * 64 + rowoff);
        const size_t tokB = (size_t)(b * 1024 + tB * 64 + rowoff);
#pragma unroll
        for (int j = 0; j < 4; ++j) {
            o[tokA * 1024 + h * 64 + j * 16 + m16] = f2b(numA[j][r] * invA);
            o[tokB * 1024 + h * 64 + j * 16 + m16] = f2b(numB[j][r] * invB);
        }
    }
}

// ---------------------------------------------------------------- launch
extern "C" void kernel_launch(void* const* d_in, const int* in_sizes, int n_in,
                              void* d_out, int out_size, void* d_ws, size_t ws_size,
                              hipStream_t stream) {
    const float* x  = (const float*)d_in[0];
    const float* Wq = (const float*)d_in[1];
    const float* Wk = (const float*)d_in[2];
    const float* Wv = (const float*)d_in[3];
    const float* Wo = (const float*)d_in[4];
    float* out = (float*)d_out;

    const size_t MEL = 4096ull * 1024ull;        // 4M elements
    u16* xb   = (u16*)d_ws;                      // 4096 x 1024
    u16* Wqkv = xb + MEL;                        // 3072 x 1024 (Wq|Wk|Wv rows)
    u16* Wob  = Wqkv + 3ull * 1024 * 1024;       // 1024 x 1024
    u16* qk   = Wob + 1024ull * 1024;            // 4096 x 2048 (q|k)
    u16* vT   = qk + 2ull * MEL;                 // [b*1024+h*64+vd][1024 tokens]
    u16* o    = vT + MEL;                        // 4096 x 1024

    cast_all<<<4096, 256, 0, stream>>>(x, Wq, Wk, Wv, Wo, xb, Wqkv);

    // R16: QKV with XCD super-tiling remap (XSWZ=1)
    dim3 gq(32, 24);   // 128^2, 768 blocks = 3/CU
    gemm_bt<128, 128, 1, 1, 1><<<gq, 256, 0, stream>>>(xb, Wqkv, qk, vT, 1024, 2048);

    // R15 best: attn XCD co-location grid (h,b,p)
    dim3 ga(16, 4, 8); // heads x batch x pair index
    based_attn<<<ga, 256, 0, stream>>>(qk, vT, o);

    dim3 go(32, 16);   // o-proj 128x64, 512 blocks = 2/CU (partition math null)
    gemm_bt<128, 64, 0, 2, 0><<<go, 256, 0, stream>>>(o, Wob, (void*)out, nullptr, 1024, 1024);
}

// Round 17
// 151.961 us; speedup vs baseline: 1.0557x; 1.0106x over previous
//
#include <hip/hip_runtime.h>

typedef unsigned short u16;
typedef __attribute__((ext_vector_type(8))) short bf16x8;   // MFMA A/B frag (8 bf16)
typedef __attribute__((ext_vector_type(4))) float f32x4;    // MFMA C/D frag

#define MFMA16(a, b, c) __builtin_amdgcn_mfma_f32_16x16x32_bf16((a), (b), (c), 0, 0, 0)

// async global->LDS, 16B per lane; LDS dest = wave-uniform base + lane*16
__device__ __forceinline__ void gll16(const void* g, void* l) {
    __builtin_amdgcn_global_load_lds(
        (const __attribute__((address_space(1))) unsigned int*)g,
        (__attribute__((address_space(3))) unsigned int*)l, 16, 0, 0);
}

__device__ __forceinline__ u16 f2b(float f) {   // f32 -> bf16 RNE (scalar)
    unsigned int u = __float_as_uint(f);
    u += 0x7fffu + ((u >> 16) & 1u);
    return (u16)(u >> 16);
}

// packed bf16x2 via HW converter (RNE)
__device__ __forceinline__ unsigned int pkcvt(float a, float b) {
    unsigned int r;
    asm("v_cvt_pk_bf16_f32 %0, %1, %2" : "=v"(r) : "v"(a), "v"(b));
    return r;
}

// ---------------------------------------------------------------- one cast kernel
__global__ __launch_bounds__(256) void cast_all(const float* __restrict__ x,
                                                const float* __restrict__ w0,
                                                const float* __restrict__ w1,
                                                const float* __restrict__ w2,
                                                const float* __restrict__ w3,
                                                u16* __restrict__ xb,
                                                u16* __restrict__ wb) {
    const int bid = blockIdx.x;
    const float* s; u16* d; int off;
    if (bid < 2048) { s = x; d = xb; off = bid; }
    else {
        const int wi = (bid - 2048) >> 9;
        s = (wi == 0) ? w0 : (wi == 1) ? w1 : (wi == 2) ? w2 : w3;
        d = wb + (size_t)wi * 1048576;
        off = (bid - 2048) & 511;
    }
    const int i = (off * 256 + threadIdx.x) * 8;
    float4 a = *(const float4*)(s + i);
    float4 b = *(const float4*)(s + i + 4);
    *(uint4*)(d + i) = make_uint4(pkcvt(a.x, a.y), pkcvt(a.z, a.w),
                                  pkcvt(b.x, b.y), pkcvt(b.z, b.w));
}

// ---------------------------------------------------------------- GEMM, dbuf K-loop
// R4-proven structure, frozen. QKV: 128x128, 768 blocks (3/CU), XSWZ=1 XCD
// super-tiling (R16 win: each XCD owns an 8x12 region -> 5MB read set, B-panel
// sharers L2-local). o-proj: 128x64, 512 blocks (2/CU), SLOTS=2, XSWZ=0
// (partition math null either way).
template <int BM, int BN, int MODE, int SLOTS, int XSWZ>
__global__ __launch_bounds__(256) void gemm_bt(const u16* __restrict__ A,
                                               const u16* __restrict__ W,
                                               void* __restrict__ Yv,
                                               u16* __restrict__ vT,
                                               int K, int ldY) {
    constexpr int MI = BM / 32, NJ = BN / 32;
    constexpr int ACH = BM / 16;
    constexpr int NPW = (BM + BN) / 64;
    __shared__ u16 As[2][SLOTS][BM * 32];
    __shared__ u16 Bs[2][SLOTS][BN * 32];
    const int t = threadIdx.x, w = t >> 6, lane = t & 63;
    const int quad = lane >> 4, m16 = lane & 15;
    const int wr = (w >> 1) * (BM / 2), wc = (w & 1) * (BN / 2);
    int bx = blockIdx.x, by = blockIdx.y;
    if constexpr (XSWZ) {                   // requires grid (32,24)
        const int id = blockIdx.x + 32 * blockIdx.y;
        const int xcd = id & 7, l = id >> 3;
        bx = (xcd & 3) * 8 + (l & 7);
        by = (xcd >> 2) * 12 + (l >> 3);
    }
    const int row0 = bx * BM, col0 = by * BN;
    const int srow = lane >> 2, scol = (lane & 3) * 8;

    auto stage = [&](int buf, int slot, int k0) {
#pragma unroll
        for (int cc = 0; cc < NPW; ++cc) {
            const int c = w * NPW + cc;
            if (c < ACH)
                gll16(A + (size_t)(row0 + c * 16 + srow) * K + k0 + scol,
                      &As[buf][slot][c * 512]);
            else
                gll16(W + (size_t)(col0 + (c - ACH) * 16 + srow) * K + k0 + scol,
                      &Bs[buf][slot][(c - ACH) * 512]);
        }
    };

    f32x4 acc[MI][NJ];
#pragma unroll
    for (int i = 0; i < MI; ++i)
#pragma unroll
        for (int j = 0; j < NJ; ++j) acc[i][j] = (f32x4){0.f, 0.f, 0.f, 0.f};

    auto compute_tile = [&](int buf, int slot) {
        bf16x8 af[MI], bf[NJ];
#pragma unroll
        for (int i = 0; i < MI; ++i)
            af[i] = *(const bf16x8*)&As[buf][slot][(wr + i * 16 + m16) * 32 + quad * 8];
#pragma unroll
        for (int j = 0; j < NJ; ++j)
            bf[j] = *(const bf16x8*)&Bs[buf][slot][(wc + j * 16 + m16) * 32 + quad * 8];
#pragma unroll
        for (int i = 0; i < MI; ++i)
#pragma unroll
            for (int j = 0; j < NJ; ++j) acc[i][j] = MFMA16(af[i], bf[j], acc[i][j]);
    };

#pragma unroll
    for (int s = 0; s < SLOTS; ++s) stage(0, s, s * 32);
    const int ngroups = K / (32 * SLOTS);
    for (int g = 0; g < ngroups; ++g) {
        const int buf = g & 1;
        __syncthreads();
        const int kn = (g + 1) * SLOTS * 32;
        if (kn < K) {
#pragma unroll
            for (int s = 0; s < SLOTS; ++s) stage(buf ^ 1, s, kn + s * 32);
        }
#pragma unroll
        for (int s = 0; s < SLOTS; ++s) compute_tile(buf, s);
    }
    if constexpr (MODE == 0) {
#pragma unroll
        for (int i = 0; i < MI; ++i)
#pragma unroll
            for (int j = 0; j < NJ; ++j)
#pragma unroll
                for (int r = 0; r < 4; ++r)
                    ((float*)Yv)[(size_t)(row0 + wr + i * 16 + quad * 4 + r) * ldY +
                                 col0 + wc + j * 16 + m16] = acc[i][j][r];
    } else {
        if (col0 < 2048) {
            u16* qk = (u16*)Yv;
#pragma unroll
            for (int i = 0; i < MI; ++i)
#pragma unroll
                for (int j = 0; j < NJ; ++j)
#pragma unroll
                    for (int r = 0; r < 4; ++r)
                        qk[(size_t)(row0 + wr + i * 16 + quad * 4 + r) * 2048 +
                           col0 + wc + j * 16 + m16] = f2b(acc[i][j][r]);
        } else {
#pragma unroll
            for (int i = 0; i < MI; ++i) {
                const int rbase = row0 + wr + i * 16;
                const int bb = rbase >> 10;
                const int tok0 = (rbase & 1023) + quad * 4;
#pragma unroll
                for (int j = 0; j < NJ; ++j) {
                    const int vTrow = bb * 1024 + (col0 + wc + j * 16 + m16 - 2048);
                    *(uint2*)(vT + (size_t)vTrow * 1024 + tok0) =
                        make_uint2(pkcvt(acc[i][j][0], acc[i][j][1]),
                                   pkcvt(acc[i][j][2], acc[i][j][3]));
                }
            }
        }
    }
}

// ---------------------------------------------------------------- based attention
// R17 = R16 best (swizzled LDS + XCD co-location) + den-from-transform:
// the QK S-frag holds 16 scores of ONE q-column (q=m16) per lane, so den is a
// free scalar sum during the transform (masked scores are 0) + a quad butterfly
// at the end. Removes the 8 den-MFMAs per 2-tile group (11% of MFMA issue),
// the `ones` operand, and 8 acc regs. Epilogue lane-map bridge: den[q] lives at
// lanes with m16=q; PV rows need q=quad*4+r -> one __shfl per r (R9-verified).
__global__ __launch_bounds__(256) void based_attn(const u16* __restrict__ qkm,
                                                  const u16* __restrict__ vT,
                                                  u16* __restrict__ o) {
    __shared__ u16 ks[2][2][2][64][32];  // [buf][slot][dblk][key][32]
    __shared__ u16 vs[2][2][2][64][32];  // [buf][slot][kb][vdim][32 keys]
    __shared__ u16 SsA[2][64][32];       // [kb][qrow][32 keys] (wave-private rows)
    __shared__ u16 SsB[2][64][32];

    const int t = threadIdx.x, w = t >> 6, lane = t & 63;
    const int quad = lane >> 4, m16 = lane & 15;
    const int h = blockIdx.x, b = blockIdx.y, p = blockIdx.z;   // XCD co-location
    const int tA = p, tB = 15 - p;
    const int srow = lane >> 2;
    const int s8x = ((lane & 3) ^ ((lane >> 3) & 3)) * 8;  // pre-swizzled src slot
    const int sx = (m16 >> 1) & 3;                          // read-side XOR factor
    const int qrow = w * 16 + m16;       // this lane's q-row (local to tile)

    const size_t qbase = (size_t)b * 1024 * 2048 + h * 64;
    const size_t kbase = qbase + 1024;
    const size_t vbase = ((size_t)b * 1024 + h * 64) * 1024;

    bf16x8 qfA[2], qfB[2];
#pragma unroll
    for (int kd = 0; kd < 2; ++kd) {
        qfA[kd] = *(const bf16x8*)(qkm + qbase +
                   (size_t)(tA * 64 + qrow) * 2048 + kd * 32 + quad * 8);
        qfB[kd] = *(const bf16x8*)(qkm + qbase +
                   (size_t)(tB * 64 + qrow) * 2048 + kd * 32 + quad * 8);
    }

    auto stage_tile = [&](int kt, int buf, int slot) {
#pragma unroll
        for (int cc = 0; cc < 2; ++cc) {
            const int c = w * 2 + cc;
            const int blk = c >> 2, rc = c & 3;
            gll16(qkm + kbase + (size_t)(kt * 64 + rc * 16 + srow) * 2048 + blk * 32 + s8x,
                  &ks[buf][slot][blk][rc * 16][0]);
            gll16(vT + vbase + (size_t)(rc * 16 + srow) * 1024 + kt * 64 + blk * 32 + s8x,
                  &vs[buf][slot][blk][rc * 16][0]);
        }
    };

    f32x4 numA[4], numB[4];
    float densA = 0.f, densB = 0.f;      // per-lane den partial for q = m16
#pragma unroll
    for (int j = 0; j < 4; ++j) numA[j] = numB[j] = (f32x4){0.f, 0.f, 0.f, 0.f};

    auto compute = [&](int buf, int slot, int kt) {
        const bool doA = (kt <= tA);
        f32x4 sA[4], sB[4];
#pragma unroll
        for (int jk = 0; jk < 4; ++jk)
            sA[jk] = sB[jk] = (f32x4){0.f, 0.f, 0.f, 0.f};
        __builtin_amdgcn_s_setprio(1);
#pragma unroll
        for (int kd = 0; kd < 2; ++kd)
#pragma unroll
            for (int jk = 0; jk < 4; ++jk) {
                bf16x8 af = *(const bf16x8*)
                    &ks[buf][slot][kd][jk * 16 + m16][(quad ^ sx) * 8];
                sB[jk] = MFMA16(af, qfB[kd], sB[jk]);
                if (doA) sA[jk] = MFMA16(af, qfA[kd], sA[jk]);
            }
        __builtin_amdgcn_s_setprio(0);
#pragma unroll
        for (int jk = 0; jk < 4; ++jk) {
            const int kl = jk * 16 + quad * 4;
            const int sidx = ((((jk & 1) * 2 + (quad >> 1)) ^ sx) << 3) +
                             ((quad & 1) << 2);
            float scB[4];
#pragma unroll
            for (int r = 0; r < 4; ++r) {
                const float u = fmaf(sB[jk][r], 0.125f, 1.0f);
                scB[r] = fmaf(u * 0.5f, u, 0.5f);
            }
            if (kt == tB) {
#pragma unroll
                for (int r = 0; r < 4; ++r)
                    if (kl + r > qrow) scB[r] = 0.f;
            }
            densB += scB[0] + scB[1] + scB[2] + scB[3];   // den for q=m16 (S col)
            *(uint2*)&SsB[jk >> 1][qrow][sidx] =
                make_uint2(pkcvt(scB[0], scB[1]), pkcvt(scB[2], scB[3]));
            if (doA) {
                float scA[4];
#pragma unroll
                for (int r = 0; r < 4; ++r) {
                    const float u = fmaf(sA[jk][r], 0.125f, 1.0f);
                    scA[r] = fmaf(u * 0.5f, u, 0.5f);
                }
                if (kt == tA) {
#pragma unroll
                    for (int r = 0; r < 4; ++r)
                        if (kl + r > qrow) scA[r] = 0.f;
                }
                densA += scA[0] + scA[1] + scA[2] + scA[3];
                *(uint2*)&SsA[jk >> 1][qrow][sidx] =
                    make_uint2(pkcvt(scA[0], scA[1]), pkcvt(scA[2], scA[3]));
            }
        }
        __builtin_amdgcn_s_setprio(1);
#pragma unroll
        for (int kb = 0; kb < 2; ++kb) {
            bf16x8 vf[4];
#pragma unroll
            for (int j = 0; j < 4; ++j)
                vf[j] = *(const bf16x8*)
                    &vs[buf][slot][kb][j * 16 + m16][(quad ^ sx) * 8];
            bf16x8 sfB = *(const bf16x8*)&SsB[kb][qrow][(quad ^ sx) * 8];
#pragma unroll
            for (int j = 0; j < 4; ++j) numB[j] = MFMA16(sfB, vf[j], numB[j]);
            if (doA) {
                bf16x8 sfA = *(const bf16x8*)&SsA[kb][qrow][(quad ^ sx) * 8];
#pragma unroll
                for (int j = 0; j < 4; ++j) numA[j] = MFMA16(sfA, vf[j], numA[j]);
            }
        }
        __builtin_amdgcn_s_setprio(0);
    };

    stage_tile(0, 0, 0);
    stage_tile(1, 0, 1);

    const int ngroups = (tB + 2) >> 1;
    for (int g = 0; g < ngroups; ++g) {
        const int buf = g & 1;
        __syncthreads();
        const int kn = (g + 1) * 2;
        if (kn <= tB) {
            stage_tile(kn, buf ^ 1, 0);
            if (kn + 1 <= tB) stage_tile(kn + 1, buf ^ 1, 1);
        }
        const int kt0 = g * 2;
        compute(buf, 0, kt0);
        if (kt0 + 1 <= tB) compute(buf, 1, kt0 + 1);
    }

    // den[q=m16] finalize: quad butterfly (all quads -> same value)
    densA += __shfl_xor(densA, 16); densA += __shfl_xor(densA, 32);
    densB += __shfl_xor(densB, 16); densB += __shfl_xor(densB, 32);

#pragma unroll
    for (int r = 0; r < 4; ++r) {
        // PV row q = quad*4+r; den[q] lives at lane with m16==q (any quad)
        const float invA = 1.0f / __shfl(densA, quad * 4 + r);
        const float invB = 1.0f / __shfl(densB, quad * 4 + r);
        const int rowoff = w * 16 + quad * 4 + r;
        const size_t tokA = (size_t)(b * 1024 + tA * 64 + rowoff);
        const size_t tokB = (size_t)(b * 1024 + tB * 64 + rowoff);
#pragma unroll
        for (int j = 0; j < 4; ++j) {
            o[tokA * 1024 + h * 64 + j * 16 + m16] = f2b(numA[j][r] * invA);
            o[tokB * 1024 + h * 64 + j * 16 + m16] = f2b(numB[j][r] * invB);
        }
    }
}

// ---------------------------------------------------------------- launch
extern "C" void kernel_launch(void* const* d_in, const int* in_sizes, int n_in,
                              void* d_out, int out_size, void* d_ws, size_t ws_size,
                              hipStream_t stream) {
    const float* x  = (const float*)d_in[0];
    const float* Wq = (const float*)d_in[1];
    const float* Wk = (const float*)d_in[2];
    const float* Wv = (const float*)d_in[3];
    const float* Wo = (const float*)d_in[4];
    float* out = (float*)d_out;

    const size_t MEL = 4096ull * 1024ull;        // 4M elements
    u16* xb   = (u16*)d_ws;                      // 4096 x 1024
    u16* Wqkv = xb + MEL;                        // 3072 x 1024 (Wq|Wk|Wv rows)
    u16* Wob  = Wqkv + 3ull * 1024 * 1024;       // 1024 x 1024
    u16* qk   = Wob + 1024ull * 1024;            // 4096 x 2048 (q|k)
    u16* vT   = qk + 2ull * MEL;                 // [b*1024+h*64+vd][1024 tokens]
    u16* o    = vT + MEL;                        // 4096 x 1024

    cast_all<<<4096, 256, 0, stream>>>(x, Wq, Wk, Wv, Wo, xb, Wqkv);

    // R16 win: QKV with XCD super-tiling remap (XSWZ=1)
    dim3 gq(32, 24);   // 128^2, 768 blocks = 3/CU
    gemm_bt<128, 128, 1, 1, 1><<<gq, 256, 0, stream>>>(xb, Wqkv, qk, vT, 1024, 2048);

    // R17: attn with den-from-transform (R15/R16 structure otherwise frozen)
    dim3 ga(16, 4, 8); // heads x batch x pair index — XCD co-location
    based_attn<<<ga, 256, 0, stream>>>(qk, vT, o);

    dim3 go(32, 16);   // o-proj 128x64, 512 blocks = 2/CU (partition math null)
    gemm_bt<128, 64, 0, 2, 0><<<go, 256, 0, stream>>>(o, Wob, (void*)out, nullptr, 1024, 1024);
}